// Round 9
// baseline (242.069 us; speedup 1.0000x reference)
//
#include <hip/hip_runtime.h>
#include <stdint.h>

// Problem constants (B, N, H, L) = (4096, 512, 1024, 8)
static constexpr int B_DIM = 4096;
static constexpr int N_DIM = 512;
static constexpr int H_DIM = 1024;
static constexpr int L_DIM = 8;
static constexpr int HL    = H_DIM * L_DIM;   // 8192
static constexpr int KC    = 2 * N_DIM;       // 1024: combW row length [W | -0.5*sum beta^2]

typedef __attribute__((ext_vector_type(8))) short short8;     // 8 bf16 (4 VGPRs)
typedef __attribute__((ext_vector_type(8))) unsigned short u16x8;
typedef __attribute__((ext_vector_type(4))) float f32x4;
typedef __attribute__((ext_vector_type(4))) unsigned int u32x4;

// round-to-nearest-even fp32 -> bf16 (bit pattern)
__device__ __forceinline__ uint16_t f2bf(float f) {
  uint32_t u = __float_as_uint(f);
  u += 0x7fffu + ((u >> 16) & 1u);
  return (uint16_t)(u >> 16);
}

__device__ __forceinline__ void stage16(const uint16_t* g, uint16_t* l) {
  __builtin_amdgcn_global_load_lds(
      (const __attribute__((address_space(1))) void*)g,
      (__attribute__((address_space(3))) void*)l, 16, 0, 0);
}

// square a bf16x8 fragment in-register -> bf16x8 (v_cvt_pk_bf16_f32 packs pairs)
__device__ __forceinline__ short8 sq8(short8 a) {
  u32x4 r;
#pragma unroll
  for (int p = 0; p < 4; ++p) {
    float f0 = __uint_as_float(((uint32_t)(uint16_t)a[2 * p])     << 16);
    float f1 = __uint_as_float(((uint32_t)(uint16_t)a[2 * p + 1]) << 16);
    float s0 = f0 * f0, s1 = f1 * f1;
    uint32_t pk;
    asm("v_cvt_pk_bf16_f32 %0, %1, %2" : "=v"(pk) : "v"(s0), "v"(s1));
    r[p] = pk;
  }
  return __builtin_bit_cast(short8, r);
}

// ---------- fused prep kernel (unchanged from v8) ----------
static constexpr int PREP_T0 = HL * N_DIM / 8;       // 524288
static constexpr int PREP_T1 = B_DIM * N_DIM / 8;    // 262144
static constexpr int PREP_T2 = H_DIM * N_DIM / 8;    // 65536

__global__ void prep_kernel(const float* __restrict__ x, const float* __restrict__ beta,
                            const float* __restrict__ W,
                            uint16_t* __restrict__ xonly, uint16_t* __restrict__ betab,
                            uint16_t* __restrict__ combW) {
  int t = blockIdx.x * 256 + threadIdx.x;
  if (t < PREP_T0) {                           // beta cast
    const f32x4* src = (const f32x4*)(beta + (size_t)t * 8);
    f32x4 a = src[0], b = src[1];
    u16x8 o;
#pragma unroll
    for (int i = 0; i < 4; ++i) { o[i] = f2bf(a[i]); o[4 + i] = f2bf(b[i]); }
    *(u16x8*)(betab + (size_t)t * 8) = o;
    return;
  }
  t -= PREP_T0;
  if (t < PREP_T1) {                           // x only (x^2 computed in-reg in fm)
    int bb = t >> 6, n8 = (t & 63) * 8;
    const f32x4* src = (const f32x4*)(x + (size_t)bb * N_DIM + n8);
    f32x4 a = src[0], b = src[1];
    u16x8 lo;
#pragma unroll
    for (int i = 0; i < 4; ++i) { lo[i] = f2bf(a[i]); lo[4 + i] = f2bf(b[i]); }
    *(u16x8*)(xonly + (size_t)bb * N_DIM + n8) = lo;
    return;
  }
  t -= PREP_T1;                                // W | -0.5*sum_l beta^2
  int h = t >> 6, n8 = (t & 63) * 8;
  const f32x4* wsrc = (const f32x4*)(W + (size_t)h * N_DIM + n8);
  f32x4 wa = wsrc[0], wb = wsrc[1];
  u16x8 lo;
#pragma unroll
  for (int i = 0; i < 4; ++i) { lo[i] = f2bf(wa[i]); lo[4 + i] = f2bf(wb[i]); }
  *(u16x8*)(combW + (size_t)h * KC + n8) = lo;
  float s[8] = {};
#pragma unroll
  for (int l = 0; l < L_DIM; ++l) {
    const f32x4* bsrc = (const f32x4*)(beta + ((size_t)h * L_DIM + l) * N_DIM + n8);
    f32x4 a = bsrc[0], b = bsrc[1];
#pragma unroll
    for (int i = 0; i < 4; ++i) { s[i] += a[i] * a[i]; s[4 + i] += b[i] * b[i]; }
  }
  u16x8 hi;
#pragma unroll
  for (int i = 0; i < 8; ++i) hi[i] = f2bf(-0.5f * s[i]);
  *(u16x8*)(combW + (size_t)h * KC + N_DIM + n8) = hi;
}

// ---------- fused GEMM v9: 128x128 tile, 256 threads, BK=128, 4 K-steps ----------
// Evidence r0/v7/v8: residency is pinned ~2 blocks/CU for 256-thread variants
// regardless of LDS (21% occupancy at 36/53/78 KB), and fm time tracks the
// number of per-step vmcnt(0) drains (8 steps=87us, 16 steps=96-112us). So v9
// minimizes latency exposures: ONE 72 KB buffer, BK=128 -> 4 steps only, r0's
// stage->sync->compute skeleton (2 syncs/step, 9 barriers/block vs 32).
// Per step each wave: 4 kk x 20 MFMA = 80 MFMA (~400cyc) -- big enough that the
// co-resident block's drain hides under it (m114 cross-block overlap).
// Swizzle: A/B rows have 16 chunks (256B); slot = chunk ^ (m&15), and m&15 == fr
// for all fragment reads -> 16 lanes hit 16 distinct slots: CONFLICT-FREE main
// loop (v8 was 2-way). W rows: 32 chunks, slot = chunk ^ (mW&7) -> 2-way (free).
// x^2 is computed in-register (sq8); W stays LDS-staged.
static constexpr int OFF_B = 16384;   // u16 offsets
static constexpr int OFF_W = 32768;
static constexpr int S_TOT = 36864;   // 72 KB

template<bool ODD>
__device__ __forceinline__ void compute_step(
    const uint16_t* __restrict__ L,
    const int (&ma)[4], const int (&mb)[4], const int (&sl)[4], const int (&wo)[4],
    f32x4 (&acc)[4][4], f32x4 (&lacc)[4])
{
#pragma unroll
  for (int kk = 0; kk < 4; ++kk) {
    short8 bf[4];
#pragma unroll
    for (int j = 0; j < 4; ++j) bf[j] = *(const short8*)(L + mb[j] + sl[kk]);
    short8 wf = *(const short8*)(L + wo[kk]);
    __builtin_amdgcn_s_setprio(1);
#pragma unroll
    for (int i = 0; i < 4; ++i) {      // full unroll: all acc indices static
      short8 a = *(const short8*)(L + ma[i] + sl[kk]);
#pragma unroll
      for (int j = 0; j < 4; ++j)
        acc[i][j] = __builtin_amdgcn_mfma_f32_16x16x32_bf16(a, bf[j], acc[i][j], 0, 0, 0);
      short8 al;
      if constexpr (ODD) al = sq8(a);  // x^2 fragment, no LDS/global traffic
      else               al = a;
      lacc[i] = __builtin_amdgcn_mfma_f32_16x16x32_bf16(al, wf, lacc[i], 0, 0, 0);
    }
    __builtin_amdgcn_s_setprio(0);
  }
}

__global__ __launch_bounds__(256) void fm_kernel(
    const uint16_t* __restrict__ xonly,   // (B, N)
    const uint16_t* __restrict__ betab,   // (HL, N)
    const uint16_t* __restrict__ combW,   // (H, KC)
    const float* __restrict__ bias,       // (H,)
    float* __restrict__ out)              // (B, H)
{
  __shared__ __align__(16) uint16_t lds[S_TOT];   // 72 KB

  const int tid  = threadIdx.x;
  const int lane = tid & 63;
  const int wave = tid >> 6;            // 0..3
  const int wm = wave >> 1, wn = wave & 1;
  const int fr = lane & 15, quad = lane >> 4;

  // bijective XCD-chunked swizzle: 2048 blocks, XCD x gets cids [256x, 256x+256)
  // within an XCD: by fastest -> same bx (B panel) stays L2-hot while A streams
  const int bid = blockIdx.x;
  const int cid = (bid & 7) * 256 + (bid >> 3);
  const int bx = cid >> 5, by = cid & 31;         // 64 x 32
  const int row0 = by * 128, col0 = bx * 128, hcol0 = bx * 16;

  // ---- staging: per thread 8 A + 8 B + 2 W chunks, pre-swizzled sources ----
  // A/B chunk s = tid + u*256: m = (tid>>4)+u*16, cp = tid&15 (const),
  // slot swz uses m&15 = (tid>>4)&15 (const) -> source col const, row += 16*u.
  const int cA = (tid & 15) ^ ((tid >> 4) & 15);
  const uint16_t* baseA = xonly + (size_t)(row0 + (tid >> 4)) * N_DIM + cA * 8;
  const uint16_t* baseB = betab + (size_t)(col0 + (tid >> 4)) * N_DIM + cA * 8;
  // W chunk s = tid + u*256 (u=0,1): mW = (tid>>5)+u*8, cpW = tid&31,
  // slot swz uses mW&7 = (tid>>5)&7 (const).
  const int cW = (tid & 31) ^ ((tid >> 5) & 7);
  const uint16_t* baseW = combW + (size_t)(hcol0 + (tid >> 5)) * KC
                        + (cW < 16 ? cW * 8 : N_DIM + (cW - 16) * 8);
  const int dT = tid * 8;

  // ---- per-thread LDS read offsets (tile-invariant, u16 units) ----
  int ma[4], mb[4], sl[4], wo[4];
#pragma unroll
  for (int i = 0; i < 4; ++i) ma[i] = (wm * 64 + i * 16 + fr) * 128;
#pragma unroll
  for (int j = 0; j < 4; ++j) mb[j] = OFF_B + (wn * 64 + j * 16 + fr) * 128;
#pragma unroll
  for (int kk = 0; kk < 4; ++kk) {
    sl[kk] = ((kk * 4 + quad) ^ fr) * 8;
    wo[kk] = OFF_W + (fr * 32 + ((wn * 16 + kk * 4 + quad) ^ (fr & 7))) * 8;
  }

  f32x4 acc[4][4] = {};
  f32x4 lacc[4]   = {};

  auto STAGE = [&](int kt) {             // 18 global_load_lds per thread
#pragma unroll
    for (int u = 0; u < 8; ++u) {
      stage16(baseA + kt + (size_t)u * 16 * N_DIM, lds + dT + u * 2048);
      stage16(baseB + kt + (size_t)u * 16 * N_DIM, lds + OFF_B + dT + u * 2048);
    }
#pragma unroll
    for (int u = 0; u < 2; ++u)
      stage16(baseW + kt + (size_t)u * 8 * KC, lds + OFF_W + dT + u * 2048);
  };

  // 4 K-steps: [sync] -> stage -> sync(drain) -> compute
#pragma unroll 1
  for (int t = 0; t < 4; ++t) {
    if (t) __syncthreads();              // WAR: all reads of the buffer done
    STAGE(t * 128);
    __syncthreads();                     // RAW: compiler drains vmcnt before barrier
    if (wn) compute_step<true >(lds, ma, mb, sl, wo, acc, lacc);
    else    compute_step<false>(lds, ma, mb, sl, wo, acc, lacc);
  }
  __syncthreads();   // all LDS reads done before red overwrites the buffer

  // ---- epilogue: lin partials + FM butterfly meet in LDS, coalesced store ----
  float* red = (float*)lds;              // 128 rows x stride 20 f32 = 10 KB
  if (!wn) {                             // x-half partial: store
#pragma unroll
    for (int i = 0; i < 4; ++i)
#pragma unroll
      for (int r = 0; r < 4; ++r)
        red[(wm * 64 + i * 16 + quad * 4 + r) * 20 + fr] = lacc[i][r];
  }
  __syncthreads();
  if (wn) {                              // x^2-half partial: add
#pragma unroll
    for (int i = 0; i < 4; ++i)
#pragma unroll
      for (int r = 0; r < 4; ++r)
        red[(wm * 64 + i * 16 + quad * 4 + r) * 20 + fr] += lacc[i][r];
  }
  __syncthreads();
  // FM: C/D col=lane&15 (hl-local), row=quad*4+r; butterfly over l bits (fr&7)
#pragma unroll
  for (int i = 0; i < 4; ++i)
#pragma unroll
    for (int j = 0; j < 4; ++j) {
      const int hin = wn * 8 + j * 2 + (fr >> 3);
#pragma unroll
      for (int r = 0; r < 4; ++r) {
        float v = acc[i][j][r];
        v = v * v;
        v += __shfl_xor(v, 1);
        v += __shfl_xor(v, 2);
        v += __shfl_xor(v, 4);
        if ((lane & 7) == 0)
          red[(wm * 64 + i * 16 + quad * 4 + r) * 20 + hin] += 0.5f * v;
      }
    }
  __syncthreads();
  {
    const int row = tid >> 1, hb = (tid & 1) * 8;   // 8 floats per thread
    const float* rp = red + row * 20 + hb;
    const float* bp = bias + hcol0 + hb;
    float* op = out + (size_t)(row0 + row) * H_DIM + hcol0 + hb;
    f32x4 v0 = *(const f32x4*)(rp);
    f32x4 v1 = *(const f32x4*)(rp + 4);
    f32x4 b0 = *(const f32x4*)(bp);
    f32x4 b1 = *(const f32x4*)(bp + 4);
    *(f32x4*)(op)     = v0 + b0;
    *(f32x4*)(op + 4) = v1 + b1;
  }
}

extern "C" void kernel_launch(void* const* d_in, const int* in_sizes, int n_in,
                              void* d_out, int out_size, void* d_ws, size_t ws_size,
                              hipStream_t stream) {
  const float* x    = (const float*)d_in[0];  // (4096, 512)
  const float* beta = (const float*)d_in[1];  // (1024, 8, 512)
  const float* W    = (const float*)d_in[2];  // (1024, 512)
  const float* bias = (const float*)d_in[3];  // (1024,)
  float* out = (float*)d_out;                 // (4096, 1024)

  uint16_t* xonly = (uint16_t*)d_ws;                        // 4096*512 bf16 = 4 MB
  uint16_t* betab = xonly + (size_t)B_DIM * N_DIM;          // 8192*512 bf16 = 8 MB
  uint16_t* combW = betab + (size_t)HL * N_DIM;             // 1024*1024 bf16 = 2 MB

  const int prep_threads = PREP_T0 + PREP_T1 + PREP_T2;     // 851968
  prep_kernel<<<prep_threads / 256, 256, 0, stream>>>(x, beta, W, xonly, betab, combW);

  // 2048 blocks (64 bx x 32 by), 128x128 tile, 4 waves, 4 K-steps of BK=128
  fm_kernel<<<2048, 256, 0, stream>>>(xonly, betab, combW, bias, out);
}